// Round 16
// baseline (532.865 us; speedup 1.0000x reference)
//
#include <hip/hip_runtime.h>
#include <hip/hip_bf16.h>
#include <hip/hip_fp16.h>

// Problem dims (hard-coded): B=8, S=4096, DIM=1024, M=1024
// Algebraic restructure: attn = x @ (mem·W)^T + (mem·b); softmax; out = probs @ mem
// Round 16: gemm_attn_1b x-prefetch moved 2 K-tiles ahead (ping-pong xrA/xrB).
// Issue order per kt is stageB THEN xload so the tile-end wait can be a
// counted vmcnt(4): B(kt+1) drained, x(kt+2) stays in flight a full kt
// (~3000 cyc >> 900 cyc HBM latency) until its xwrite. Removes the per-kt
// xwrite stall (x was loaded and consumed within the same kt, ~500 cyc cover).
// Everything else identical to r15 (best, 492.4 us).
#define KDIM 1024

typedef __attribute__((ext_vector_type(8))) __bf16    bf16x8;
typedef __attribute__((ext_vector_type(4))) __bf16    bf16x4;
typedef __attribute__((ext_vector_type(8))) _Float16  half8;
typedef __attribute__((ext_vector_type(4))) _Float16  half4v;
typedef __attribute__((ext_vector_type(4))) float     f32x4;

// async global->LDS, 16B per lane. LDS base must be wave-uniform; HW adds lane*16.
__device__ __forceinline__ void g2l16(const void* g, void* l) {
  __builtin_amdgcn_global_load_lds(
      (const __attribute__((address_space(1))) unsigned int*)g,
      (__attribute__((address_space(3))) unsigned int*)l, 16, 0, 0);
}

__device__ __forceinline__ void split2(float v, __bf16& h, __bf16& l) {
  h = (__bf16)v;
  l = (__bf16)(v - (float)h);
}

// ---------------------------------------------------------------------------
// prep_all: all four prep kernels as block ranges of one dispatch (r13).
//   [0, 4096)     split_mem        (mem -> Mh/Ml bf16 hi/lo)
//   [4096, 5120)  transpose_split_W (W -> Wth/Wtl, B^T layout)
//   [5120, 5632)  build_memTb      (mem -> fp16 MFMA-fragment pack)
//   [5632, 5888)  bias_c           (cvec = mem @ b)
__global__ __launch_bounds__(256) void prep_all(
    const float* __restrict__ mem, const float* __restrict__ W,
    const float* __restrict__ b,
    __bf16* __restrict__ Mh, __bf16* __restrict__ Ml,
    __bf16* __restrict__ Wth, __bf16* __restrict__ Wtl,
    _Float16* __restrict__ memTb, float* __restrict__ cvec) {
  const int bid = blockIdx.x;
  const int t = threadIdx.x;

  if (bid < 4096) {
    // ---- split_mem
    const int i = bid * 256 + t;
    __bf16 h, l;
    split2(mem[i], h, l);
    Mh[i] = h; Ml[i] = l;
  } else if (bid < 5120) {
    // ---- transpose_split_W  (was grid (32,32), threads (32,8))
    __shared__ float tl[32][33];
    const int f = bid - 4096;
    const int bx = f & 31, by = f >> 5;
    const int tx = t & 31, ty = t >> 5;
#pragma unroll
    for (int j = 0; j < 4; ++j)
      tl[ty + 8 * j][tx] = W[(by * 32 + ty + 8 * j) * 1024 + bx * 32 + tx];
    __syncthreads();
#pragma unroll
    for (int j = 0; j < 4; ++j) {
      float v = tl[tx][ty + 8 * j];
      __bf16 h, l;
      split2(v, h, l);
      const int idx = (bx * 32 + ty + 8 * j) * 1024 + by * 32 + tx;
      Wth[idx] = h; Wtl[idx] = l;
    }
  } else if (bid < 5632) {
    // ---- build_memTb (coalesced LDS-tiled pack; fragment f = nt*32 + kt,
    //      entry (lane l, j) = (fp16) mem[kt*32 + (l>>4)*8 + j][nt*16 + (l&15)])
    __shared__ float tile[32][65];
    const int f = bid - 5120;
    const int kt = f >> 4;       // 0..31
    const int ct = f & 15;       // 0..15 (64-col group)
    {
      const int r = t >> 3;
      const int c = (t & 7) * 8;
      const float4 v0 = *(const float4*)(mem + (size_t)(kt * 32 + r) * 1024 + ct * 64 + c);
      const float4 v1 = *(const float4*)(mem + (size_t)(kt * 32 + r) * 1024 + ct * 64 + c + 4);
      tile[r][c + 0] = v0.x; tile[r][c + 1] = v0.y; tile[r][c + 2] = v0.z; tile[r][c + 3] = v0.w;
      tile[r][c + 4] = v1.x; tile[r][c + 5] = v1.y; tile[r][c + 6] = v1.z; tile[r][c + 7] = v1.w;
    }
    __syncthreads();
    const int ntl = t >> 6;
    const int l = t & 63;
    const int nt = ct * 4 + ntl;
    const int fr = nt * 32 + kt;
    half8 o;
#pragma unroll
    for (int j = 0; j < 8; ++j)
      o[j] = (_Float16)tile[(l >> 4) * 8 + j][ntl * 16 + (l & 15)];
    *(half8*)(memTb + (size_t)(fr * 64 + l) * 8) = o;
  } else {
    // ---- bias_c: c[row] = sum_e b[e] * mem[row][e], one wave per row
    const int wave = t >> 6, lane = t & 63;
    const int row = (bid - 5632) * 4 + wave;
    float s = 0.f;
#pragma unroll
    for (int j = 0; j < 16; ++j) {
      const int e = lane + 64 * j;
      s += b[e] * mem[row * 1024 + e];
    }
#pragma unroll
    for (int off = 32; off; off >>= 1) s += __shfl_xor(s, off);
    if (lane == 0) cvec[row] = s;
  }
}

// ---------------------------------------------------------------------------
// Split-bf16 compensated GEMM for the small P = mem @ W product
// (128x128 tile, known-good structure). Epilogue writes C as bf16 hi/lo.
__global__ __launch_bounds__(256) void gemm_p(
    const __bf16* __restrict__ Agh, const __bf16* __restrict__ Agl,
    const __bf16* __restrict__ Bgh, const __bf16* __restrict__ Bgl,
    __bf16* __restrict__ Oh, __bf16* __restrict__ Ol) {
  __shared__ __attribute__((aligned(16))) __bf16 Ah[128 * 32];
  __shared__ __attribute__((aligned(16))) __bf16 Al[128 * 32];
  __shared__ __attribute__((aligned(16))) __bf16 Bh[128 * 32];
  __shared__ __attribute__((aligned(16))) __bf16 Bl[128 * 32];

  const int t = threadIdx.x;
  const int wave = t >> 6;
  const int lane = t & 63;
  const int wm = wave & 1, wn = wave >> 1;

  const int nwg = gridDim.x * gridDim.y;
  int flat = blockIdx.y * gridDim.x + blockIdx.x;
  if ((nwg & 7) == 0) {
    const int cpx = nwg >> 3;
    flat = (flat & 7) * cpx + (flat >> 3);
  }
  const int tileN = (flat % gridDim.x) * 128;
  const int tileM = (flat / gridDim.x) * 128;

  f32x4 acc[4][4] = {};

  const int rS = lane >> 2;
  const int cS = (lane & 3) * 8;

  for (int kt = 0; kt < KDIM / 32; ++kt) {
    const int k0 = kt * 32;
    __syncthreads();
#pragma unroll
    for (int i = 0; i < 2; ++i) {
      const int rb = i * 64 + wave * 16;
      const int grb = (tileN + rb + rS) * KDIM + k0 + cS;
      g2l16(Bgh + grb, &Bh[rb * 32]);
      g2l16(Bgl + grb, &Bl[rb * 32]);
      const int gra = (tileM + rb + rS) * KDIM + k0 + cS;
      g2l16(Agh + gra, &Ah[rb * 32]);
      g2l16(Agl + gra, &Al[rb * 32]);
    }
    __syncthreads();

    const int fr = lane & 15;
    const int fk = (lane >> 4) * 8;
    bf16x8 afh[4], afl[4], bfh[4], bfl[4];
#pragma unroll
    for (int mf = 0; mf < 4; ++mf) {
      const int r = wm * 64 + mf * 16 + fr;
      afh[mf] = *(const bf16x8*)(&Ah[r * 32 + fk]);
      afl[mf] = *(const bf16x8*)(&Al[r * 32 + fk]);
    }
#pragma unroll
    for (int nf = 0; nf < 4; ++nf) {
      const int r = wn * 64 + nf * 16 + fr;
      bfh[nf] = *(const bf16x8*)(&Bh[r * 32 + fk]);
      bfl[nf] = *(const bf16x8*)(&Bl[r * 32 + fk]);
    }
#pragma unroll
    for (int mf = 0; mf < 4; ++mf)
#pragma unroll
      for (int nf = 0; nf < 4; ++nf) {
        acc[mf][nf] = __builtin_amdgcn_mfma_f32_16x16x32_bf16(afh[mf], bfh[nf], acc[mf][nf], 0, 0, 0);
        acc[mf][nf] = __builtin_amdgcn_mfma_f32_16x16x32_bf16(afh[mf], bfl[nf], acc[mf][nf], 0, 0, 0);
        acc[mf][nf] = __builtin_amdgcn_mfma_f32_16x16x32_bf16(afl[mf], bfh[nf], acc[mf][nf], 0, 0, 0);
      }
  }

  const int er = (lane >> 4) * 4;
  const int ec = lane & 15;
#pragma unroll
  for (int nf = 0; nf < 4; ++nf) {
    const int col = tileN + wn * 64 + nf * 16 + ec;
#pragma unroll
    for (int mf = 0; mf < 4; ++mf) {
#pragma unroll
      for (int r = 0; r < 4; ++r) {
        const int row = tileM + wm * 64 + mf * 16 + er + r;
        const size_t idx = (size_t)row * KDIM + col;
        float v = acc[mf][nf][r];
        __bf16 h = (__bf16)v;
        Oh[idx] = h;
        Ol[idx] = (__bf16)(v - (float)h);
      }
    }
  }
}

// ---------------------------------------------------------------------------
// attn = x @ P^T + c : 256x256 tile, BK=32, 8 waves, ONE barrier per K-tile.
// Round 16: x prefetched 2 K-tiles ahead (xrA/xrB ping-pong). Per-kt VMEM
// issue order: stageB(kt+1) then xload(kt+2); tile-end waits vmcnt(4)
// (B drained, x flies). xwrite consumes x loaded a full kt earlier.
// mm3 order identical to r11/r15 -> bit-identical attn.
__global__ __launch_bounds__(512, 2) void gemm_attn_1b(
    const float* __restrict__ X,
    const __bf16* __restrict__ Pgh, const __bf16* __restrict__ Pgl,
    const float* __restrict__ bias,
    float* __restrict__ Of) {
  __shared__ __attribute__((aligned(16))) __bf16 AhL[2 * 8192];
  __shared__ __attribute__((aligned(16))) __bf16 AlL[2 * 8192];
  __shared__ __attribute__((aligned(16))) __bf16 BhL[2 * 8192];
  __shared__ __attribute__((aligned(16))) __bf16 BlL[2 * 8192];

  const int t = threadIdx.x;
  const int wave = t >> 6, lane = t & 63;
  const int wm = wave >> 2;        // 2 M-halves (128 rows each)
  const int wn = wave & 3;         // 4 N-quarters (64 cols each)

  // XCD-aware bijective remap; nwg = 4*128 = 512
  int flat = blockIdx.y * 4 + blockIdx.x;
  flat = (flat & 7) * 64 + (flat >> 3);
  const int tileN = (flat & 3) * 256;
  const int tileM = (flat >> 2) * 256;

  // ---- staging geometry (identical to r6/r11)
  int rowB_[2], gsB_[2], ldsB_[2];
#pragma unroll
  for (int i = 0; i < 2; ++i) {
    const int f16 = i * 512 + t;
    rowB_[i] = f16 >> 2;
    const int slot = f16 & 3;
    gsB_[i] = slot ^ ((rowB_[i] >> 1) & 3);       // pre-swizzled src col group
    ldsB_[i] = (i * 512 + wave * 64) * 8;         // wave-uniform elem base
  }
  int rowA_[4], colA_[4], physA_[4];
#pragma unroll
  for (int i = 0; i < 4; ++i) {
    const int f4 = i * 512 + t;
    rowA_[i] = f4 >> 3;
    const int col8 = f4 & 7;
    colA_[i] = col8 * 4;
    physA_[i] = rowA_[i] * 64 +
                ((((col8 >> 1) ^ ((rowA_[i] >> 1) & 3)) << 4)) + (col8 & 1) * 8;
  }

  const int fr = lane & 15;
  const int sc = lane >> 4;
  const int swF = (fr >> 1) & 3;
  const int fragoff = ((sc ^ swF) << 4);

  f32x4 acc[8][4] = {};
  f32x4 xrA[4], xrB[4];

  auto xload = [&](f32x4 (&dst)[4], int k0) {
#pragma unroll
    for (int i = 0; i < 4; ++i)
      dst[i] = *(const f32x4*)(X + (size_t)(tileM + rowA_[i]) * 1024 + k0 + colA_[i]);
  };
  auto stageB = [&](int buf, int k0) {
#pragma unroll
    for (int i = 0; i < 2; ++i) {
      const size_t g = (size_t)(tileN + rowB_[i]) * 1024 + k0 + gsB_[i] * 8;
      g2l16(Pgh + g, &BhL[buf * 8192 + ldsB_[i]]);
      g2l16(Pgl + g, &BlL[buf * 8192 + ldsB_[i]]);
    }
  };
  auto xwrite = [&](const f32x4 (&src)[4], int buf) {
#pragma unroll
    for (int i = 0; i < 4; ++i) {
      bf16x4 h, l;
#pragma unroll
      for (int j = 0; j < 4; ++j) {
        const float vj = src[i][j];
        __bf16 hh = (__bf16)vj;
        h[j] = hh;
        l[j] = (__bf16)(vj - (float)hh);
      }
      *(bf16x4*)((char*)AhL + buf * 16384 + physA_[i]) = h;
      *(bf16x4*)((char*)AlL + buf * 16384 + physA_[i]) = l;
    }
  };
  auto mm3 = [&](f32x4& a, const bf16x8& ah, const bf16x8& al,
                 const bf16x8& bh, const bf16x8& bl) {
    a = __builtin_amdgcn_mfma_f32_16x16x32_bf16(ah, bh, a, 0, 0, 0);
    a = __builtin_amdgcn_mfma_f32_16x16x32_bf16(ah, bl, a, 0, 0, 0);
    a = __builtin_amdgcn_mfma_f32_16x16x32_bf16(al, bh, a, 0, 0, 0);
  };

  // body(kt): consumes xr[(kt+1)&1] (x(kt+1), loaded at body(kt-1) or
  // prologue), loads xr[kt&1] = x(kt+2).
  auto body = [&](int kt, f32x4 (&xcons)[4], f32x4 (&xldst)[4]) {
    const int cur = kt & 1, nxt = cur ^ 1;
    bf16x8 ah[4], al[4], bh[4], bl[4];

    // ---- read B n0-3 + A m0-3 from buf cur; issue B(kt+1) then x(kt+2)
#pragma unroll
    for (int nf = 0; nf < 4; ++nf) {
      const int row = wn * 64 + nf * 16 + fr;
      const int off = cur * 16384 + row * 64 + fragoff;
      bh[nf] = *(const bf16x8*)((const char*)BhL + off);
      bl[nf] = *(const bf16x8*)((const char*)BlL + off);
    }
#pragma unroll
    for (int mf = 0; mf < 4; ++mf) {
      const int row = wm * 128 + mf * 16 + fr;
      const int off = cur * 16384 + row * 64 + fragoff;
      ah[mf] = *(const bf16x8*)((const char*)AhL + off);
      al[mf] = *(const bf16x8*)((const char*)AlL + off);
    }
    if (kt < 31) stageB(nxt, (kt + 1) * 32);   // B first (FIFO: drained at tile-end)
    if (kt < 30) xload(xldst, (kt + 2) * 32);  // x second (flies across barrier)

    // ---- MFMA m0-3 x n0-3 (compiler inserts fine-grained lgkmcnt)
    __builtin_amdgcn_s_setprio(1);
#pragma unroll
    for (int mf = 0; mf < 4; ++mf)
#pragma unroll
      for (int nf = 0; nf < 4; ++nf)
        mm3(acc[mf][nf], ah[mf], al[mf], bh[nf], bl[nf]);
    __builtin_amdgcn_s_setprio(0);

    // ---- read A m4-7; split+write next-tile A (x was loaded a full kt ago)
#pragma unroll
    for (int mf = 0; mf < 4; ++mf) {
      const int row = wm * 128 + (4 + mf) * 16 + fr;
      const int off = cur * 16384 + row * 64 + fragoff;
      ah[mf] = *(const bf16x8*)((const char*)AhL + off);
      al[mf] = *(const bf16x8*)((const char*)AlL + off);
    }
    if (kt < 31) xwrite(xcons, nxt);

    // ---- MFMA m4-7 x n0-3
    __builtin_amdgcn_s_setprio(1);
#pragma unroll
    for (int mf = 0; mf < 4; ++mf)
#pragma unroll
      for (int nf = 0; nf < 4; ++nf)
        mm3(acc[4 + mf][nf], ah[mf], al[mf], bh[nf], bl[nf]);
    __builtin_amdgcn_s_setprio(0);

    // ---- tile-end sync: drain B(kt+1) only; x(kt+2) stays in flight
    if (kt < 30)
      asm volatile("s_waitcnt vmcnt(4) lgkmcnt(0)" ::: "memory");
    else
      asm volatile("s_waitcnt vmcnt(0) lgkmcnt(0)" ::: "memory");
    __builtin_amdgcn_s_barrier();
  };

  // ---- prologue: stage K-tile 0 into buffer 0; x(1) prefetched into xrB
  xload(xrA, 0);            // x(0)
  stageB(0, 0);             // B(0)
  xwrite(xrA, 0);           // compiler waits x(0) (vmcnt(4)); B(0) flies
  xload(xrB, 32);           // x(1) in flight across the barrier
  asm volatile("s_waitcnt vmcnt(4) lgkmcnt(0)" ::: "memory");  // B(0) done
  __builtin_amdgcn_s_barrier();

  for (int kt = 0; kt < 32; kt += 2) {
    body(kt,     xrB, xrA);   // even: consume x(kt+1)=xrB, load x(kt+2)->xrA
    body(kt + 1, xrA, xrB);   // odd:  consume xrA, load -> xrB
  }

  // ---- epilogue: C/D layout col = lane&15, row = (lane>>4)*4 + reg; + bias
  const int er = (lane >> 4) * 4;
  const int ec = lane & 15;
#pragma unroll
  for (int nf = 0; nf < 4; ++nf) {
    const int col = tileN + wn * 64 + nf * 16 + ec;
    const float bv = bias[col];
#pragma unroll
    for (int mf = 0; mf < 8; ++mf) {
#pragma unroll
      for (int r = 0; r < 4; ++r) {
        const int row = tileM + wm * 128 + mf * 16 + er + r;
        Of[(size_t)row * 1024 + col] = acc[mf][nf][r] + bv;
      }
    }
  }
}

// ---------------------------------------------------------------------------
// Fused softmax + context GEMM, 64 rows/block, depth-3 B register pipeline
// (r9 structure + r15 nt streaming hints). Unchanged.
__global__ __launch_bounds__(512, 2) void fused_softmax_ctx64(
    const float* __restrict__ attn, const _Float16* __restrict__ memTb,
    float* __restrict__ out) {
  __shared__ __attribute__((aligned(16))) _Float16 P[64 * 1024];  // 128 KB

  const int t = threadIdx.x;
  const int wave = t >> 6, lane = t & 63;
  const int riw = lane >> 4;       // row within wave's 4-row group
  const int cg = lane & 15;        // col group (16 threads per row)
  const size_t grow0 = (size_t)blockIdx.x * 64;

  const char* bb = (const char*)memTb + (size_t)(wave * 256) * 1024 + lane * 16;

  // --- softmax: two passes of 32 rows (rows p*32 + wave*4 + riw)
#pragma unroll
  for (int p = 0; p < 2; ++p) {
    const int row = p * 32 + wave * 4 + riw;
    f32x4 v[16];
    {
      const f32x4* arow = (const f32x4*)(attn + (grow0 + row) * 1024);
#pragma unroll
      for (int j = 0; j < 16; ++j)
        v[j] = __builtin_nontemporal_load(arow + cg + j * 16);
    }
    float m = -1e30f;
#pragma unroll
    for (int j = 0; j < 16; ++j)
      m = fmaxf(m, fmaxf(fmaxf(v[j].x, v[j].y), fmaxf(v[j].z, v[j].w)));
#pragma unroll
    for (int off = 1; off < 16; off <<= 1) m = fmaxf(m, __shfl_xor(m, off));

    float s = 0.f;
#pragma unroll
    for (int j = 0; j < 16; ++j) {
      v[j].x = expf(v[j].x - m);
      v[j].y = expf(v[j].y - m);
      v[j].z = expf(v[j].z - m);
      v[j].w = expf(v[j].w - m);
      s += (v[j].x + v[j].y) + (v[j].z + v[j].w);
    }
#pragma unroll
    for (int off = 1; off < 16; off <<= 1) s += __shfl_xor(s, off);
    const float inv = 1.0f / s;

    const int swz = (row & 7) << 4;
    char* rbase = (char*)P + row * 2048;
#pragma unroll
    for (int j = 0; j < 16; ++j) {
      half4v o;
      o[0] = (_Float16)(v[j].x * inv);
      o[1] = (_Float16)(v[j].y * inv);
      o[2] = (_Float16)(v[j].z * inv);
      o[3] = (_Float16)(v[j].w * inv);
      const int byteoff = (cg * 8 + j * 128) ^ swz;   // 8B-aligned, bijective
      *(half4v*)(rbase + byteoff) = o;
    }
  }

  // prefetch B-frags for kt=0,1,2 (stay in flight across the barrier)
  half8 b0[8], b1[8], b2[8];
#pragma unroll
  for (int nf = 0; nf < 8; ++nf)
    b0[nf] = *(const half8*)(bb + nf * 32768);
#pragma unroll
  for (int nf = 0; nf < 8; ++nf)
    b1[nf] = *(const half8*)(bb + nf * 32768 + 1024);
#pragma unroll
  for (int nf = 0; nf < 8; ++nf)
    b2[nf] = *(const half8*)(bb + nf * 32768 + 2048);

  __syncthreads();

  // --- context GEMM: out[64 rows][wave's 128 cols] = P @ mem
  const int fr = lane & 15;
  const int fko = (lane >> 4) * 8;   // k element offset within 32
  f32x4 acc[4][8] = {};

  auto step = [&](half8 (&bc)[8], int kt) {
    half8 a[4];
#pragma unroll
    for (int mf = 0; mf < 4; ++mf) {
      const int ar = mf * 16 + fr;
      const int kbyte = ((kt * 32 + fko) * 2) ^ ((ar & 7) << 4);
      a[mf] = *(const half8*)((const char*)P + ar * 2048 + kbyte);
    }
#pragma unroll
    for (int mf = 0; mf < 4; ++mf)
#pragma unroll
      for (int nf = 0; nf < 8; ++nf)
        acc[mf][nf] = __builtin_amdgcn_mfma_f32_16x16x32_f16(a[mf], bc[nf], acc[mf][nf], 0, 0, 0);
    if (kt + 3 < 32) {
#pragma unroll
      for (int nf = 0; nf < 8; ++nf)
        bc[nf] = *(const half8*)(bb + nf * 32768 + (kt + 3) * 1024);
    }
  };

  for (int kt = 0; kt < 30; kt += 3) {
    step(b0, kt);
    step(b1, kt + 1);
    step(b2, kt + 2);
  }
  step(b0, 30);
  step(b1, 31);

  // --- epilogue. C/D layout: col = lane&15, row = (lane>>4)*4 + reg
  //     (nontemporal: out is write-once streaming)
  const int colbase = wave * 128;
  const int er = (lane >> 4) * 4;
  const int ec = lane & 15;
#pragma unroll
  for (int mf = 0; mf < 4; ++mf)
#pragma unroll
    for (int nf = 0; nf < 8; ++nf) {
      const int col = colbase + nf * 16 + ec;
#pragma unroll
      for (int r = 0; r < 4; ++r)
        __builtin_nontemporal_store(
            acc[mf][nf][r], &out[(grow0 + mf * 16 + er + r) * 1024 + col]);
    }
}

// ---------------------------------------------------------------------------
extern "C" void kernel_launch(void* const* d_in, const int* in_sizes, int n_in,
                              void* d_out, int out_size, void* d_ws, size_t ws_size,
                              hipStream_t stream) {
  const float* x   = (const float*)d_in[0];   // [32768][1024]
  const float* W   = (const float*)d_in[1];   // [1024][1024]  (out=e, in=d)
  const float* b   = (const float*)d_in[2];   // [1024]
  const float* mem = (const float*)d_in[3];   // [1024][1024]  (m, e)
  float* out = (float*)d_out;

  char* ws = (char*)d_ws;
  const size_t MB = 1024 * 1024;
  float*    attn  = (float*)(ws);              // 128 MB
  __bf16*   Mh    = (__bf16*)(ws + 192 * MB);  // 2 MB
  __bf16*   Ml    = (__bf16*)(ws + 194 * MB);  // 2 MB
  __bf16*   Wth   = (__bf16*)(ws + 196 * MB);  // 2 MB
  __bf16*   Wtl   = (__bf16*)(ws + 198 * MB);  // 2 MB
  __bf16*   Ph    = (__bf16*)(ws + 200 * MB);  // 2 MB
  __bf16*   Pl    = (__bf16*)(ws + 202 * MB);  // 2 MB
  _Float16* memTb = (_Float16*)(ws + 204 * MB);// 2 MB
  float*    cvec  = (float*)(ws + 206 * MB);   // 4 KB

  // all preps in ONE dispatch
  prep_all<<<5888, 256, 0, stream>>>(mem, W, b, Mh, Ml, Wth, Wtl, memTb, cvec);

  // P = mem @ W  (split-bf16, out split bf16)
  gemm_p<<<dim3(8, 8), 256, 0, stream>>>(Mh, Ml, Wth, Wtl, Ph, Pl);

  // attn = x @ P^T + c  (256x256, 1 barrier/K-tile, x prefetched 2 kt ahead)
  gemm_attn_1b<<<dim3(4, 128), 512, 0, stream>>>(x, Ph, Pl, cvec, attn);

  // fused softmax + context = probs @ mem  (r9 depth-3 + nt streaming hints)
  fused_softmax_ctx64<<<512, 512, 0, stream>>>(attn, memTb, out);
}

// Round 17
// 492.366 us; speedup vs baseline: 1.0823x; 1.0823x over previous
//
#include <hip/hip_runtime.h>
#include <hip/hip_bf16.h>
#include <hip/hip_fp16.h>

// Problem dims (hard-coded): B=8, S=4096, DIM=1024, M=1024
// Algebraic restructure: attn = x @ (mem·W)^T + (mem·b); softmax; out = probs @ mem
// Round 17: FINAL — revert to r15 exactly (best measured: 492.4 us).
// r16's 2-ahead x-prefetch regressed (VGPR cliff -> spill, MfmaUtil 43->35),
// reproducing r7's failure; the compiler's 1-ahead schedule is optimal at
// this register budget. Session: 627.6 -> 492.4 us, absmax 0.03125 throughout.
#define KDIM 1024

typedef __attribute__((ext_vector_type(8))) __bf16    bf16x8;
typedef __attribute__((ext_vector_type(4))) __bf16    bf16x4;
typedef __attribute__((ext_vector_type(8))) _Float16  half8;
typedef __attribute__((ext_vector_type(4))) _Float16  half4v;
typedef __attribute__((ext_vector_type(4))) float     f32x4;

// async global->LDS, 16B per lane. LDS base must be wave-uniform; HW adds lane*16.
__device__ __forceinline__ void g2l16(const void* g, void* l) {
  __builtin_amdgcn_global_load_lds(
      (const __attribute__((address_space(1))) unsigned int*)g,
      (__attribute__((address_space(3))) unsigned int*)l, 16, 0, 0);
}

__device__ __forceinline__ void split2(float v, __bf16& h, __bf16& l) {
  h = (__bf16)v;
  l = (__bf16)(v - (float)h);
}

// ---------------------------------------------------------------------------
// prep_all: all four prep kernels as block ranges of one dispatch.
//   [0, 4096)     split_mem        (mem -> Mh/Ml bf16 hi/lo)
//   [4096, 5120)  transpose_split_W (W -> Wth/Wtl, B^T layout)
//   [5120, 5632)  build_memTb      (mem -> fp16 MFMA-fragment pack)
//   [5632, 5888)  bias_c           (cvec = mem @ b)
__global__ __launch_bounds__(256) void prep_all(
    const float* __restrict__ mem, const float* __restrict__ W,
    const float* __restrict__ b,
    __bf16* __restrict__ Mh, __bf16* __restrict__ Ml,
    __bf16* __restrict__ Wth, __bf16* __restrict__ Wtl,
    _Float16* __restrict__ memTb, float* __restrict__ cvec) {
  const int bid = blockIdx.x;
  const int t = threadIdx.x;

  if (bid < 4096) {
    // ---- split_mem
    const int i = bid * 256 + t;
    __bf16 h, l;
    split2(mem[i], h, l);
    Mh[i] = h; Ml[i] = l;
  } else if (bid < 5120) {
    // ---- transpose_split_W  (was grid (32,32), threads (32,8))
    __shared__ float tl[32][33];
    const int f = bid - 4096;
    const int bx = f & 31, by = f >> 5;
    const int tx = t & 31, ty = t >> 5;
#pragma unroll
    for (int j = 0; j < 4; ++j)
      tl[ty + 8 * j][tx] = W[(by * 32 + ty + 8 * j) * 1024 + bx * 32 + tx];
    __syncthreads();
#pragma unroll
    for (int j = 0; j < 4; ++j) {
      float v = tl[tx][ty + 8 * j];
      __bf16 h, l;
      split2(v, h, l);
      const int idx = (bx * 32 + ty + 8 * j) * 1024 + by * 32 + tx;
      Wth[idx] = h; Wtl[idx] = l;
    }
  } else if (bid < 5632) {
    // ---- build_memTb (coalesced LDS-tiled pack; fragment f = nt*32 + kt,
    //      entry (lane l, j) = (fp16) mem[kt*32 + (l>>4)*8 + j][nt*16 + (l&15)])
    __shared__ float tile[32][65];
    const int f = bid - 5120;
    const int kt = f >> 4;       // 0..31
    const int ct = f & 15;       // 0..15 (64-col group)
    {
      const int r = t >> 3;
      const int c = (t & 7) * 8;
      const float4 v0 = *(const float4*)(mem + (size_t)(kt * 32 + r) * 1024 + ct * 64 + c);
      const float4 v1 = *(const float4*)(mem + (size_t)(kt * 32 + r) * 1024 + ct * 64 + c + 4);
      tile[r][c + 0] = v0.x; tile[r][c + 1] = v0.y; tile[r][c + 2] = v0.z; tile[r][c + 3] = v0.w;
      tile[r][c + 4] = v1.x; tile[r][c + 5] = v1.y; tile[r][c + 6] = v1.z; tile[r][c + 7] = v1.w;
    }
    __syncthreads();
    const int ntl = t >> 6;
    const int l = t & 63;
    const int nt = ct * 4 + ntl;
    const int fr = nt * 32 + kt;
    half8 o;
#pragma unroll
    for (int j = 0; j < 8; ++j)
      o[j] = (_Float16)tile[(l >> 4) * 8 + j][ntl * 16 + (l & 15)];
    *(half8*)(memTb + (size_t)(fr * 64 + l) * 8) = o;
  } else {
    // ---- bias_c: c[row] = sum_e b[e] * mem[row][e], one wave per row
    const int wave = t >> 6, lane = t & 63;
    const int row = (bid - 5632) * 4 + wave;
    float s = 0.f;
#pragma unroll
    for (int j = 0; j < 16; ++j) {
      const int e = lane + 64 * j;
      s += b[e] * mem[row * 1024 + e];
    }
#pragma unroll
    for (int off = 32; off; off >>= 1) s += __shfl_xor(s, off);
    if (lane == 0) cvec[row] = s;
  }
}

// ---------------------------------------------------------------------------
// Split-bf16 compensated GEMM for the small P = mem @ W product
// (128x128 tile, known-good structure). Epilogue writes C as bf16 hi/lo.
__global__ __launch_bounds__(256) void gemm_p(
    const __bf16* __restrict__ Agh, const __bf16* __restrict__ Agl,
    const __bf16* __restrict__ Bgh, const __bf16* __restrict__ Bgl,
    __bf16* __restrict__ Oh, __bf16* __restrict__ Ol) {
  __shared__ __attribute__((aligned(16))) __bf16 Ah[128 * 32];
  __shared__ __attribute__((aligned(16))) __bf16 Al[128 * 32];
  __shared__ __attribute__((aligned(16))) __bf16 Bh[128 * 32];
  __shared__ __attribute__((aligned(16))) __bf16 Bl[128 * 32];

  const int t = threadIdx.x;
  const int wave = t >> 6;
  const int lane = t & 63;
  const int wm = wave & 1, wn = wave >> 1;

  const int nwg = gridDim.x * gridDim.y;
  int flat = blockIdx.y * gridDim.x + blockIdx.x;
  if ((nwg & 7) == 0) {
    const int cpx = nwg >> 3;
    flat = (flat & 7) * cpx + (flat >> 3);
  }
  const int tileN = (flat % gridDim.x) * 128;
  const int tileM = (flat / gridDim.x) * 128;

  f32x4 acc[4][4] = {};

  const int rS = lane >> 2;
  const int cS = (lane & 3) * 8;

  for (int kt = 0; kt < KDIM / 32; ++kt) {
    const int k0 = kt * 32;
    __syncthreads();
#pragma unroll
    for (int i = 0; i < 2; ++i) {
      const int rb = i * 64 + wave * 16;
      const int grb = (tileN + rb + rS) * KDIM + k0 + cS;
      g2l16(Bgh + grb, &Bh[rb * 32]);
      g2l16(Bgl + grb, &Bl[rb * 32]);
      const int gra = (tileM + rb + rS) * KDIM + k0 + cS;
      g2l16(Agh + gra, &Ah[rb * 32]);
      g2l16(Agl + gra, &Al[rb * 32]);
    }
    __syncthreads();

    const int fr = lane & 15;
    const int fk = (lane >> 4) * 8;
    bf16x8 afh[4], afl[4], bfh[4], bfl[4];
#pragma unroll
    for (int mf = 0; mf < 4; ++mf) {
      const int r = wm * 64 + mf * 16 + fr;
      afh[mf] = *(const bf16x8*)(&Ah[r * 32 + fk]);
      afl[mf] = *(const bf16x8*)(&Al[r * 32 + fk]);
    }
#pragma unroll
    for (int nf = 0; nf < 4; ++nf) {
      const int r = wn * 64 + nf * 16 + fr;
      bfh[nf] = *(const bf16x8*)(&Bh[r * 32 + fk]);
      bfl[nf] = *(const bf16x8*)(&Bl[r * 32 + fk]);
    }
#pragma unroll
    for (int mf = 0; mf < 4; ++mf)
#pragma unroll
      for (int nf = 0; nf < 4; ++nf) {
        acc[mf][nf] = __builtin_amdgcn_mfma_f32_16x16x32_bf16(afh[mf], bfh[nf], acc[mf][nf], 0, 0, 0);
        acc[mf][nf] = __builtin_amdgcn_mfma_f32_16x16x32_bf16(afh[mf], bfl[nf], acc[mf][nf], 0, 0, 0);
        acc[mf][nf] = __builtin_amdgcn_mfma_f32_16x16x32_bf16(afl[mf], bfh[nf], acc[mf][nf], 0, 0, 0);
      }
  }

  const int er = (lane >> 4) * 4;
  const int ec = lane & 15;
#pragma unroll
  for (int nf = 0; nf < 4; ++nf) {
    const int col = tileN + wn * 64 + nf * 16 + ec;
#pragma unroll
    for (int mf = 0; mf < 4; ++mf) {
#pragma unroll
      for (int r = 0; r < 4; ++r) {
        const int row = tileM + wm * 64 + mf * 16 + er + r;
        const size_t idx = (size_t)row * KDIM + col;
        float v = acc[mf][nf][r];
        __bf16 h = (__bf16)v;
        Oh[idx] = h;
        Ol[idx] = (__bf16)(v - (float)h);
      }
    }
  }
}

// ---------------------------------------------------------------------------
// attn = x @ P^T + c : 256x256 tile, BK=32, 8 waves, ONE barrier per K-tile.
// EXACT r11/r13/r15 version (best measured: 210-214 us, MfmaUtil 43,
// 0 bank conflicts, VGPR 124). Double-buffered LDS; the compiler's 1-ahead
// x-load schedule is optimal at this register budget (r7/r16 both regressed
// with deeper prefetch).
__global__ __launch_bounds__(512, 2) void gemm_attn_1b(
    const float* __restrict__ X,
    const __bf16* __restrict__ Pgh, const __bf16* __restrict__ Pgl,
    const float* __restrict__ bias,
    float* __restrict__ Of) {
  __shared__ __attribute__((aligned(16))) __bf16 AhL[2 * 8192];
  __shared__ __attribute__((aligned(16))) __bf16 AlL[2 * 8192];
  __shared__ __attribute__((aligned(16))) __bf16 BhL[2 * 8192];
  __shared__ __attribute__((aligned(16))) __bf16 BlL[2 * 8192];

  const int t = threadIdx.x;
  const int wave = t >> 6, lane = t & 63;
  const int wm = wave >> 2;        // 2 M-halves (128 rows each)
  const int wn = wave & 3;         // 4 N-quarters (64 cols each)

  // XCD-aware bijective remap; nwg = 4*128 = 512
  int flat = blockIdx.y * 4 + blockIdx.x;
  flat = (flat & 7) * 64 + (flat >> 3);
  const int tileN = (flat & 3) * 256;
  const int tileM = (flat >> 2) * 256;

  // ---- staging geometry
  int rowB_[2], gsB_[2], ldsB_[2];
#pragma unroll
  for (int i = 0; i < 2; ++i) {
    const int f16 = i * 512 + t;
    rowB_[i] = f16 >> 2;
    const int slot = f16 & 3;
    gsB_[i] = slot ^ ((rowB_[i] >> 1) & 3);       // pre-swizzled src col group
    ldsB_[i] = (i * 512 + wave * 64) * 8;         // wave-uniform elem base
  }
  int rowA_[4], colA_[4], physA_[4];
#pragma unroll
  for (int i = 0; i < 4; ++i) {
    const int f4 = i * 512 + t;
    rowA_[i] = f4 >> 3;
    const int col8 = f4 & 7;
    colA_[i] = col8 * 4;
    physA_[i] = rowA_[i] * 64 +
                ((((col8 >> 1) ^ ((rowA_[i] >> 1) & 3)) << 4)) + (col8 & 1) * 8;
  }

  const int fr = lane & 15;
  const int sc = lane >> 4;
  const int swF = (fr >> 1) & 3;
  const int fragoff = ((sc ^ swF) << 4);

  f32x4 acc[8][4] = {};
  f32x4 xr[4];

  auto xload = [&](int k0) {
#pragma unroll
    for (int i = 0; i < 4; ++i)
      xr[i] = *(const f32x4*)(X + (size_t)(tileM + rowA_[i]) * 1024 + k0 + colA_[i]);
  };
  auto stageB = [&](int buf, int k0) {
#pragma unroll
    for (int i = 0; i < 2; ++i) {
      const size_t g = (size_t)(tileN + rowB_[i]) * 1024 + k0 + gsB_[i] * 8;
      g2l16(Pgh + g, &BhL[buf * 8192 + ldsB_[i]]);
      g2l16(Pgl + g, &BlL[buf * 8192 + ldsB_[i]]);
    }
  };
  auto xwrite = [&](int buf) {
#pragma unroll
    for (int i = 0; i < 4; ++i) {
      bf16x4 h, l;
#pragma unroll
      for (int j = 0; j < 4; ++j) {
        const float vj = xr[i][j];
        __bf16 hh = (__bf16)vj;
        h[j] = hh;
        l[j] = (__bf16)(vj - (float)hh);
      }
      *(bf16x4*)((char*)AhL + buf * 16384 + physA_[i]) = h;
      *(bf16x4*)((char*)AlL + buf * 16384 + physA_[i]) = l;
    }
  };
  auto mm3 = [&](f32x4& a, const bf16x8& ah, const bf16x8& al,
                 const bf16x8& bh, const bf16x8& bl) {
    a = __builtin_amdgcn_mfma_f32_16x16x32_bf16(ah, bh, a, 0, 0, 0);
    a = __builtin_amdgcn_mfma_f32_16x16x32_bf16(ah, bl, a, 0, 0, 0);
    a = __builtin_amdgcn_mfma_f32_16x16x32_bf16(al, bh, a, 0, 0, 0);
  };

  // ---- prologue: stage K-tile 0 into buffer 0
  xload(0);
  stageB(0, 0);
  xwrite(0);   // compiler emits counted vmcnt for xr; B(0) stays in flight
  asm volatile("s_waitcnt vmcnt(0) lgkmcnt(0)" ::: "memory");
  __builtin_amdgcn_s_barrier();

  int cur = 0;
  for (int kt = 0; kt < 32; ++kt) {
    const int nxt = cur ^ 1;
    const int k1 = (kt + 1) * 32;
    bf16x8 ah[4], al[4], bh[4], bl[4];

    // ---- read B n0-3 + A m0-3 from buf cur; issue next-tile x loads + B stage
#pragma unroll
    for (int nf = 0; nf < 4; ++nf) {
      const int row = wn * 64 + nf * 16 + fr;
      const int off = cur * 16384 + row * 64 + fragoff;
      bh[nf] = *(const bf16x8*)((const char*)BhL + off);
      bl[nf] = *(const bf16x8*)((const char*)BlL + off);
    }
#pragma unroll
    for (int mf = 0; mf < 4; ++mf) {
      const int row = wm * 128 + mf * 16 + fr;
      const int off = cur * 16384 + row * 64 + fragoff;
      ah[mf] = *(const bf16x8*)((const char*)AhL + off);
      al[mf] = *(const bf16x8*)((const char*)AlL + off);
    }
    if (kt < 31) { xload(k1); stageB(nxt, k1); }

    // ---- MFMA m0-3 x n0-3 (compiler inserts fine-grained lgkmcnt)
    __builtin_amdgcn_s_setprio(1);
#pragma unroll
    for (int mf = 0; mf < 4; ++mf)
#pragma unroll
      for (int nf = 0; nf < 4; ++nf)
        mm3(acc[mf][nf], ah[mf], al[mf], bh[nf], bl[nf]);
    __builtin_amdgcn_s_setprio(0);

    // ---- read A m4-7; split+write next-tile A (auto-waits x, B flies)
#pragma unroll
    for (int mf = 0; mf < 4; ++mf) {
      const int row = wm * 128 + (4 + mf) * 16 + fr;
      const int off = cur * 16384 + row * 64 + fragoff;
      ah[mf] = *(const bf16x8*)((const char*)AhL + off);
      al[mf] = *(const bf16x8*)((const char*)AlL + off);
    }
    if (kt < 31) xwrite(nxt);

    // ---- MFMA m4-7 x n0-3
    __builtin_amdgcn_s_setprio(1);
#pragma unroll
    for (int mf = 0; mf < 4; ++mf)
#pragma unroll
      for (int nf = 0; nf < 4; ++nf)
        mm3(acc[4 + mf][nf], ah[mf], al[mf], bh[nf], bl[nf]);
    __builtin_amdgcn_s_setprio(0);

    // ---- tile-end sync: B(kt+1)/A-writes complete (issued ~2-3K cyc ago)
    asm volatile("s_waitcnt vmcnt(0) lgkmcnt(0)" ::: "memory");
    __builtin_amdgcn_s_barrier();
    cur = nxt;
  }

  // ---- epilogue: C/D layout col = lane&15, row = (lane>>4)*4 + reg; + bias
  const int er = (lane >> 4) * 4;
  const int ec = lane & 15;
#pragma unroll
  for (int nf = 0; nf < 4; ++nf) {
    const int col = tileN + wn * 64 + nf * 16 + ec;
    const float bv = bias[col];
#pragma unroll
    for (int mf = 0; mf < 8; ++mf) {
#pragma unroll
      for (int r = 0; r < 4; ++r) {
        const int row = tileM + wm * 128 + mf * 16 + er + r;
        Of[(size_t)row * 1024 + col] = acc[mf][nf][r] + bv;
      }
    }
  }
}

// ---------------------------------------------------------------------------
// Fused softmax + context GEMM, 64 rows/block, depth-3 B register pipeline
// (r9 structure + r15 nt streaming hints).
__global__ __launch_bounds__(512, 2) void fused_softmax_ctx64(
    const float* __restrict__ attn, const _Float16* __restrict__ memTb,
    float* __restrict__ out) {
  __shared__ __attribute__((aligned(16))) _Float16 P[64 * 1024];  // 128 KB

  const int t = threadIdx.x;
  const int wave = t >> 6, lane = t & 63;
  const int riw = lane >> 4;       // row within wave's 4-row group
  const int cg = lane & 15;        // col group (16 threads per row)
  const size_t grow0 = (size_t)blockIdx.x * 64;

  const char* bb = (const char*)memTb + (size_t)(wave * 256) * 1024 + lane * 16;

  // --- softmax: two passes of 32 rows (rows p*32 + wave*4 + riw)
#pragma unroll
  for (int p = 0; p < 2; ++p) {
    const int row = p * 32 + wave * 4 + riw;
    f32x4 v[16];
    {
      const f32x4* arow = (const f32x4*)(attn + (grow0 + row) * 1024);
#pragma unroll
      for (int j = 0; j < 16; ++j)
        v[j] = __builtin_nontemporal_load(arow + cg + j * 16);
    }
    float m = -1e30f;
#pragma unroll
    for (int j = 0; j < 16; ++j)
      m = fmaxf(m, fmaxf(fmaxf(v[j].x, v[j].y), fmaxf(v[j].z, v[j].w)));
#pragma unroll
    for (int off = 1; off < 16; off <<= 1) m = fmaxf(m, __shfl_xor(m, off));

    float s = 0.f;
#pragma unroll
    for (int j = 0; j < 16; ++j) {
      v[j].x = expf(v[j].x - m);
      v[j].y = expf(v[j].y - m);
      v[j].z = expf(v[j].z - m);
      v[j].w = expf(v[j].w - m);
      s += (v[j].x + v[j].y) + (v[j].z + v[j].w);
    }
#pragma unroll
    for (int off = 1; off < 16; off <<= 1) s += __shfl_xor(s, off);
    const float inv = 1.0f / s;

    const int swz = (row & 7) << 4;
    char* rbase = (char*)P + row * 2048;
#pragma unroll
    for (int j = 0; j < 16; ++j) {
      half4v o;
      o[0] = (_Float16)(v[j].x * inv);
      o[1] = (_Float16)(v[j].y * inv);
      o[2] = (_Float16)(v[j].z * inv);
      o[3] = (_Float16)(v[j].w * inv);
      const int byteoff = (cg * 8 + j * 128) ^ swz;   // 8B-aligned, bijective
      *(half4v*)(rbase + byteoff) = o;
    }
  }

  // prefetch B-frags for kt=0,1,2 (stay in flight across the barrier)
  half8 b0[8], b1[8], b2[8];
#pragma unroll
  for (int nf = 0; nf < 8; ++nf)
    b0[nf] = *(const half8*)(bb + nf * 32768);
#pragma unroll
  for (int nf = 0; nf < 8; ++nf)
    b1[nf] = *(const half8*)(bb + nf * 32768 + 1024);
#pragma unroll
  for (int nf = 0; nf < 8; ++nf)
    b2[nf] = *(const half8*)(bb + nf * 32768 + 2048);

  __syncthreads();

  // --- context GEMM: out[64 rows][wave's 128 cols] = P @ mem
  const int fr = lane & 15;
  const int fko = (lane >> 4) * 8;   // k element offset within 32
  f32x4 acc[4][8] = {};

  auto step = [&](half8 (&bc)[8], int kt) {
    half8 a[4];
#pragma unroll
    for (int mf = 0; mf < 4; ++mf) {
      const int ar = mf * 16 + fr;
      const int kbyte = ((kt * 32 + fko) * 2) ^ ((ar & 7) << 4);
      a[mf] = *(const half8*)((const char*)P + ar * 2048 + kbyte);
    }
#pragma unroll
    for (int mf = 0; mf < 4; ++mf)
#pragma unroll
      for (int nf = 0; nf < 8; ++nf)
        acc[mf][nf] = __builtin_amdgcn_mfma_f32_16x16x32_f16(a[mf], bc[nf], acc[mf][nf], 0, 0, 0);
    if (kt + 3 < 32) {
#pragma unroll
      for (int nf = 0; nf < 8; ++nf)
        bc[nf] = *(const half8*)(bb + nf * 32768 + (kt + 3) * 1024);
    }
  };

  for (int kt = 0; kt < 30; kt += 3) {
    step(b0, kt);
    step(b1, kt + 1);
    step(b2, kt + 2);
  }
  step(b0, 30);
  step(b1, 31);

  // --- epilogue. C/D layout: col = lane&15, row = (lane>>4)*4 + reg
  //     (nontemporal: out is write-once streaming)
  const int colbase = wave * 128;
  const int er = (lane >> 4) * 4;
  const int ec = lane & 15;
#pragma unroll
  for (int mf = 0; mf < 4; ++mf)
#pragma unroll
    for (int nf = 0; nf < 8; ++nf) {
      const int col = colbase + nf * 16 + ec;
#pragma unroll
      for (int r = 0; r < 4; ++r)
        __builtin_nontemporal_store(
            acc[mf][nf][r], &out[(grow0 + mf * 16 + er + r) * 1024 + col]);
    }
}

// ---------------------------------------------------------------------------
extern "C" void kernel_launch(void* const* d_in, const int* in_sizes, int n_in,
                              void* d_out, int out_size, void* d_ws, size_t ws_size,
                              hipStream_t stream) {
  const float* x   = (const float*)d_in[0];   // [32768][1024]
  const float* W   = (const float*)d_in[1];   // [1024][1024]  (out=e, in=d)
  const float* b   = (const float*)d_in[2];   // [1024]
  const float* mem = (const float*)d_in[3];   // [1024][1024]  (m, e)
  float* out = (float*)d_out;

  char* ws = (char*)d_ws;
  const size_t MB = 1024 * 1024;
  float*    attn  = (float*)(ws);              // 128 MB
  __bf16*   Mh    = (__bf16*)(ws + 192 * MB);  // 2 MB
  __bf16*   Ml    = (__bf16*)(ws + 194 * MB);  // 2 MB
  __bf16*   Wth   = (__bf16*)(ws + 196 * MB);  // 2 MB
  __bf16*   Wtl   = (__bf16*)(ws + 198 * MB);  // 2 MB
  __bf16*   Ph    = (__bf16*)(ws + 200 * MB);  // 2 MB
  __bf16*   Pl    = (__bf16*)(ws + 202 * MB);  // 2 MB
  _Float16* memTb = (_Float16*)(ws + 204 * MB);// 2 MB
  float*    cvec  = (float*)(ws + 206 * MB);   // 4 KB

  // all preps in ONE dispatch
  prep_all<<<5888, 256, 0, stream>>>(mem, W, b, Mh, Ml, Wth, Wtl, memTb, cvec);

  // P = mem @ W  (split-bf16, out split bf16)
  gemm_p<<<dim3(8, 8), 256, 0, stream>>>(Mh, Ml, Wth, Wtl, Ph, Pl);

  // attn = x @ P^T + c  (r11 exact: 256x256, 1 barrier/K-tile)
  gemm_attn_1b<<<dim3(4, 128), 512, 0, stream>>>(x, Ph, Pl, cvec, attn);

  // fused softmax + context = probs @ mem  (r9 depth-3 + nt streaming hints)
  fused_softmax_ctx64<<<512, 512, 0, stream>>>(attn, memTb, out);
}